// Round 4
// baseline (837.291 us; speedup 1.0000x reference)
//
#include <hip/hip_runtime.h>
#include <cstdint>
#include <cstddef>

// ===========================================================================
// GCN: out = D^{-1/2}(A+I)D^{-1/2} (dropout(x)@W) + b
// Strategy: no global atomics. LDS-partitioned scatter:
//   node space split into NP partitions (partition accumulator lives in LDS),
//   grid = NP x B; block (p,s) scans edge-slice s, accumulates rows of
//   partition p into LDS, flushes coalesced partials; reduce kernel sums.
// Algebra: g[n] = dinv[n]*h[n];  out[n] = b + dinv[n]*(g[n] + sum_e w*g[col]).
// ===========================================================================

#define R_EDGE_MAX 6250    // rows/partition (edge): 6250*2*4B = 50 KB LDS
#define R_DEG_MAX  12500   // rows/partition (deg):  12500*4B  = 50 KB LDS

// ---------------------------------------------------------------------------
// Threefry-2x32, 20 rounds, key=(0,42): JAX partitionable-threefry bernoulli.
// per element j: (o0,o1)=threefry(0, j); keep <=> ((o0^o1)>>31)==0
// ---------------------------------------------------------------------------
__device__ __forceinline__ uint32_t rotl32(uint32_t x, int r) {
    return (x << r) | (x >> (32 - r));
}

__device__ __forceinline__ void threefry2x32(uint32_t x0, uint32_t x1,
                                             uint32_t& o0, uint32_t& o1) {
    const uint32_t k0 = 0u, k1 = 42u;
    const uint32_t k2 = k0 ^ k1 ^ 0x1BD11BDAu;
    x0 += k0; x1 += k1;
#define TF_R4(a, b, c, d)                                         \
    x0 += x1; x1 = rotl32(x1, a); x1 ^= x0;                       \
    x0 += x1; x1 = rotl32(x1, b); x1 ^= x0;                       \
    x0 += x1; x1 = rotl32(x1, c); x1 ^= x0;                       \
    x0 += x1; x1 = rotl32(x1, d); x1 ^= x0;
    TF_R4(13, 15, 26, 6)   x0 += k1; x1 += k2 + 1u;
    TF_R4(17, 29, 16, 24)  x0 += k2; x1 += k0 + 2u;
    TF_R4(13, 15, 26, 6)   x0 += k0; x1 += k1 + 3u;
    TF_R4(17, 29, 16, 24)  x0 += k1; x1 += k2 + 4u;
    TF_R4(13, 15, 26, 6)   x0 += k2; x1 += k0 + 5u;
#undef TF_R4
    o0 = x0; o1 = x1;
}

// ---------------------------------------------------------------------------
// deg partitioned scan: block (p,s): LDS-accumulate w over rows of partition p
// within edge slice s; flush partial_deg[s][pR .. pR+rows)
// ---------------------------------------------------------------------------
__global__ __launch_bounds__(256) void k_deg_scan(const int* __restrict__ row,
                                                  const float* __restrict__ w,
                                                  float* __restrict__ partial,
                                                  int E, int N, int R, int NP, int B) {
    __shared__ float sdeg[R_DEG_MAX];
    const int p = blockIdx.x % NP;
    const int s = blockIdx.x / NP;
    const int pR = p * R;
    const int rows = min(R, N - pR);
    for (int i = threadIdx.x; i < rows; i += blockDim.x) sdeg[i] = 0.f;
    __syncthreads();
    const long long e0 = (long long)E * s / B;
    const long long e1 = (long long)E * (s + 1) / B;
    for (long long e = e0 + threadIdx.x; e < e1; e += blockDim.x) {
        int r = row[e];
        unsigned rr = (unsigned)(r - pR);
        if (rr < (unsigned)rows) {
            atomicAdd(&sdeg[rr], w[e]);   // ds_add_f32, LDS-local
        }
    }
    __syncthreads();
    float* dst = partial + (size_t)s * N + pR;
    for (int i = threadIdx.x; i < rows; i += blockDim.x) dst[i] = sdeg[i];
}

// ---------------------------------------------------------------------------
// dinv[n] = rsqrt(1 + sum_s partial[s][n])    (self-loop weight folded)
// ---------------------------------------------------------------------------
__global__ void k_finish_deg(const float* __restrict__ partial,
                             float* __restrict__ dinv, int N, int B) {
    int n = blockIdx.x * blockDim.x + threadIdx.x;
    if (n >= N) return;
    float acc = 1.0f;
    for (int s = 0; s < B; ++s) acc += partial[(size_t)s * N + n];
    dinv[n] = rsqrtf(acc);
}

// ---------------------------------------------------------------------------
// g = dinv * (dropout(x) @ W)   ([N,512]@[512,2] -> [N,2])
// one wave per node; lane l owns f in [8l,8l+8); one threefry per element
// ---------------------------------------------------------------------------
__global__ __launch_bounds__(256) void k_h(const float* __restrict__ x,
                                           const float* __restrict__ W,
                                           const float* __restrict__ dinv,
                                           float* __restrict__ g,
                                           int N, int F) {
    const int wave = (int)((blockIdx.x * blockDim.x + threadIdx.x) >> 6);
    const int lane = threadIdx.x & 63;
    if (wave >= N) return;
    const int m = wave;
    const int f0 = lane * 8;

    const float4* xa = (const float4*)(x + (size_t)m * F + f0);
    float4 a0 = xa[0], a1 = xa[1];
    float va[8] = {a0.x, a0.y, a0.z, a0.w, a1.x, a1.y, a1.z, a1.w};

    const uint32_t jbase = (uint32_t)m * (uint32_t)F + (uint32_t)f0;
    float acc0 = 0.f, acc1 = 0.f;

#pragma unroll
    for (int t = 0; t < 8; ++t) {
        uint32_t o0, o1;
        threefry2x32(0u, jbase + (uint32_t)t, o0, o1);
        uint32_t bits = o0 ^ o1;
        float xv = (bits >> 31) ? 0.0f : va[t] * 2.0f;   // 1/(1-0.5)=2
        acc0 += xv * W[(f0 + t) * 2 + 0];
        acc1 += xv * W[(f0 + t) * 2 + 1];
    }
#pragma unroll
    for (int off = 32; off >= 1; off >>= 1) {
        acc0 += __shfl_xor(acc0, off);
        acc1 += __shfl_xor(acc1, off);
    }
    if (lane == 0) {
        float d = dinv[m];
        g[(size_t)m * 2 + 0] = d * acc0;
        g[(size_t)m * 2 + 1] = d * acc1;
    }
}

// ---------------------------------------------------------------------------
// edge partitioned scan: LDS[rr] += w * g[col]; flush partial[s][n][2]
// ---------------------------------------------------------------------------
__global__ __launch_bounds__(256) void k_edge_scan(const int* __restrict__ row,
                                                   const int* __restrict__ col,
                                                   const float* __restrict__ w,
                                                   const float* __restrict__ g,
                                                   float* __restrict__ partial,
                                                   int E, int N, int R, int NP, int B) {
    __shared__ float sacc[R_EDGE_MAX * 2];
    const int p = blockIdx.x % NP;
    const int s = blockIdx.x / NP;
    const int pR = p * R;
    const int rows = min(R, N - pR);
    for (int i = threadIdx.x; i < rows * 2; i += blockDim.x) sacc[i] = 0.f;
    __syncthreads();
    const float2* g2 = (const float2*)g;
    const long long e0 = (long long)E * s / B;
    const long long e1 = (long long)E * (s + 1) / B;
    for (long long e = e0 + threadIdx.x; e < e1; e += blockDim.x) {
        int r = row[e];
        unsigned rr = (unsigned)(r - pR);
        if (rr < (unsigned)rows) {
            float wv = w[e];
            int c = col[e];
            float2 gv = g2[c];
            atomicAdd(&sacc[rr * 2 + 0], wv * gv.x);
            atomicAdd(&sacc[rr * 2 + 1], wv * gv.y);
        }
    }
    __syncthreads();
    float* dst = partial + ((size_t)s * N + pR) * 2;
    for (int i = threadIdx.x; i < rows * 2; i += blockDim.x) dst[i] = sacc[i];
}

// ---------------------------------------------------------------------------
// out[n] = b + dinv[n] * (g[n] + sum_s partial[s][n])
// ---------------------------------------------------------------------------
__global__ void k_final(const float* __restrict__ partial,
                        const float* __restrict__ g,
                        const float* __restrict__ dinv,
                        const float* __restrict__ b,
                        float* __restrict__ out, int N, int B) {
    int n = blockIdx.x * blockDim.x + threadIdx.x;
    if (n >= N) return;
    const float2* p2 = (const float2*)partial;
    float2 gv = ((const float2*)g)[n];
    float a0 = gv.x, a1 = gv.y;
    for (int s = 0; s < B; ++s) {
        float2 pv = p2[(size_t)s * N + n];
        a0 += pv.x; a1 += pv.y;
    }
    float d = dinv[n];
    float2 o;
    o.x = b[0] + d * a0;
    o.y = b[1] + d * a1;
    ((float2*)out)[n] = o;
}

// ------------------------- fallback (atomic) path --------------------------
__global__ void k_deg_atomic(const int* __restrict__ row, const float* __restrict__ w,
                             float* __restrict__ deg, int E) {
    int e = blockIdx.x * blockDim.x + threadIdx.x;
    if (e < E) atomicAdd(&deg[row[e]], w[e]);
}
__global__ void k_dinv_fb(float* __restrict__ deg, int N) {
    int n = blockIdx.x * blockDim.x + threadIdx.x;
    if (n < N) deg[n] = rsqrtf(deg[n] + 1.0f);
}
__global__ void k_selfinit_fb(const float* __restrict__ g, const float* __restrict__ dinv,
                              const float* __restrict__ b, float* __restrict__ out, int N) {
    int n = blockIdx.x * blockDim.x + threadIdx.x;
    if (n < N) {
        float d = dinv[n];
        float2 gv = ((const float2*)g)[n];
        float2 o;
        o.x = b[0] + d * gv.x;
        o.y = b[1] + d * gv.y;
        ((float2*)out)[n] = o;
    }
}
__global__ void k_edge_atomic(const int* __restrict__ row, const int* __restrict__ col,
                              const float* __restrict__ w, const float* __restrict__ dinv,
                              const float* __restrict__ g, float* __restrict__ out, int E) {
    int e = blockIdx.x * blockDim.x + threadIdx.x;
    if (e < E) {
        int r = row[e], c = col[e];
        float nrm = dinv[r] * w[e];
        float2 gv = ((const float2*)g)[c];
        atomicAdd(&out[(size_t)r * 2 + 0], nrm * gv.x);
        atomicAdd(&out[(size_t)r * 2 + 1], nrm * gv.y);
    }
}

extern "C" void kernel_launch(void* const* d_in, const int* in_sizes, int n_in,
                              void* d_out, int out_size, void* d_ws, size_t ws_size,
                              hipStream_t stream) {
    const float* x  = (const float*)d_in[0];
    const int*   ei = (const int*)d_in[1];
    const float* ew = (const float*)d_in[2];
    const float* W  = (const float*)d_in[3];
    const float* b  = (const float*)d_in[4];
    float* out = (float*)d_out;

    const int C = in_sizes[4];            // 2
    const int F = in_sizes[3] / C;        // 512
    const int N = in_sizes[0] / F;        // 100000
    const int E = in_sizes[1] / 2;        // 3200000
    const int* row = ei;
    const int* col = ei + E;

    // workspace layout: dinv[N] | g[2N] | partials[B*2N] (deg reuses as B_D*N)
    float* dinv = (float*)d_ws;
    float* g    = dinv + N;
    float* part = g + (size_t)2 * N;
    const size_t ws_floats = ws_size / sizeof(float);
    const size_t avail = (ws_floats > (size_t)3 * N) ? ws_floats - (size_t)3 * N : 0;

    int B_E = (int)(avail / ((size_t)2 * N));  if (B_E > 64) B_E = 64;
    int B_D = (int)(avail / (size_t)N);        if (B_D > 64) B_D = 64;

    const int NP_E = (N + R_EDGE_MAX - 1) / R_EDGE_MAX;
    const int NP_D = (N + R_DEG_MAX - 1) / R_DEG_MAX;
    const int R_E = (N + NP_E - 1) / NP_E;
    const int R_D = (N + NP_D - 1) / NP_D;

    if (B_E >= 2 && B_D >= 2) {
        // partitioned, atomic-free path
        k_deg_scan<<<NP_D * B_D, 256, 0, stream>>>(row, ew, part, E, N, R_D, NP_D, B_D);
        k_finish_deg<<<(N + 255) / 256, 256, 0, stream>>>(part, dinv, N, B_D);
        k_h<<<(N + 3) / 4, 256, 0, stream>>>(x, W, dinv, g, N, F);
        k_edge_scan<<<NP_E * B_E, 256, 0, stream>>>(row, col, ew, g, part, E, N, R_E, NP_E, B_E);
        k_final<<<(N + 255) / 256, 256, 0, stream>>>(part, g, dinv, b, out, N, B_E);
    } else {
        // fallback: global-atomic path (round-3 verified)
        hipMemsetAsync(dinv, 0, (size_t)N * sizeof(float), stream);
        k_deg_atomic<<<(E + 255) / 256, 256, 0, stream>>>(row, ew, dinv, E);
        k_dinv_fb<<<(N + 255) / 256, 256, 0, stream>>>(dinv, N);
        k_h<<<(N + 3) / 4, 256, 0, stream>>>(x, W, dinv, g, N, F);
        k_selfinit_fb<<<(N + 255) / 256, 256, 0, stream>>>(g, dinv, b, out, N);
        k_edge_atomic<<<(E + 255) / 256, 256, 0, stream>>>(row, col, ew, dinv, g, out, E);
    }
}

// Round 5
// 496.646 us; speedup vs baseline: 1.6859x; 1.6859x over previous
//
#include <hip/hip_runtime.h>
#include <cstdint>
#include <cstddef>

// ===========================================================================
// GCN: out = D^{-1/2}(A+I)D^{-1/2} (dropout(x)@W) + b
// Pipeline (atomic-free):
//   1. k_deg_scan   : partitioned LDS accumulation of deg (unconditional
//                     int4 row + float4 w streams, predicated ds-atomics)
//   2. k_finish_deg : dinv = rsqrt(1 + sum partials)
//   3. k_h          : g = dinv * (dropout(x) @ W)   (threefry bernoulli)
//   4. k_vpre       : v2[e] = w[e] * g[col[e]]      (coalesced gather pass)
//   5. k_edge_scan  : partitioned LDS accumulation of sum w*g[col] per row
//   6. k_final      : out = b + dinv * (g + sum partials)
// ===========================================================================

#define R_DEG  12500   // rows/partition (deg):  12500*4B       = 50 KB LDS
#define R_EDGE 6250    // rows/partition (edge): 6250*2ch*4B    = 50 KB LDS

// ---------------------------------------------------------------------------
// Threefry-2x32, 20 rounds, key=(0,42): JAX partitionable-threefry bernoulli.
// per element j: (o0,o1)=threefry(0, j); keep <=> ((o0^o1)>>31)==0
// ---------------------------------------------------------------------------
__device__ __forceinline__ uint32_t rotl32(uint32_t x, int r) {
    return (x << r) | (x >> (32 - r));
}

__device__ __forceinline__ void threefry2x32(uint32_t x0, uint32_t x1,
                                             uint32_t& o0, uint32_t& o1) {
    const uint32_t k0 = 0u, k1 = 42u;
    const uint32_t k2 = k0 ^ k1 ^ 0x1BD11BDAu;
    x0 += k0; x1 += k1;
#define TF_R4(a, b, c, d)                                         \
    x0 += x1; x1 = rotl32(x1, a); x1 ^= x0;                       \
    x0 += x1; x1 = rotl32(x1, b); x1 ^= x0;                       \
    x0 += x1; x1 = rotl32(x1, c); x1 ^= x0;                       \
    x0 += x1; x1 = rotl32(x1, d); x1 ^= x0;
    TF_R4(13, 15, 26, 6)   x0 += k1; x1 += k2 + 1u;
    TF_R4(17, 29, 16, 24)  x0 += k2; x1 += k0 + 2u;
    TF_R4(13, 15, 26, 6)   x0 += k0; x1 += k1 + 3u;
    TF_R4(17, 29, 16, 24)  x0 += k1; x1 += k2 + 4u;
    TF_R4(13, 15, 26, 6)   x0 += k2; x1 += k0 + 5u;
#undef TF_R4
    o0 = x0; o1 = x1;
}

// ---------------------------------------------------------------------------
// 1. deg partitioned scan: unconditional int4 row + float4 w streams.
//    block (p,s): accumulate w over rows of partition p in slice s.
// ---------------------------------------------------------------------------
__global__ __launch_bounds__(512) void k_deg_scan(const int* __restrict__ row,
                                                  const float* __restrict__ w,
                                                  float* __restrict__ partial,
                                                  int E, int N, int R, int NP, int B) {
    __shared__ float sdeg[R_DEG];
    const int p = blockIdx.x % NP;
    const int s = blockIdx.x / NP;
    const int pR = p * R;
    const unsigned rows = (unsigned)min(R, N - pR);
    for (int i = threadIdx.x; i < R; i += 512) sdeg[i] = 0.f;
    __syncthreads();

    const int E4 = E >> 2;
    const int4*   rows4 = (const int4*)row;
    const float4* w4    = (const float4*)w;
    const long long q0 = (long long)E4 * s / B;
    const long long q1 = (long long)E4 * (s + 1) / B;
    for (long long q = q0 + threadIdx.x; q < q1; q += 512) {
        int4   r4 = rows4[q];
        float4 wv = w4[q];
        unsigned a0 = (unsigned)(r4.x - pR);
        unsigned a1 = (unsigned)(r4.y - pR);
        unsigned a2 = (unsigned)(r4.z - pR);
        unsigned a3 = (unsigned)(r4.w - pR);
        if (a0 < rows) atomicAdd(&sdeg[a0], wv.x);
        if (a1 < rows) atomicAdd(&sdeg[a1], wv.y);
        if (a2 < rows) atomicAdd(&sdeg[a2], wv.z);
        if (a3 < rows) atomicAdd(&sdeg[a3], wv.w);
    }
    // scalar tail (E not divisible by 4)
    if (s == B - 1) {
        for (int e = 4 * E4 + threadIdx.x; e < E; e += 512) {
            unsigned a = (unsigned)(row[e] - pR);
            if (a < rows) atomicAdd(&sdeg[a], w[e]);
        }
    }
    __syncthreads();
    float* dst = partial + (size_t)s * N + pR;
    for (int i = threadIdx.x; i < (int)rows; i += 512) dst[i] = sdeg[i];
}

// ---------------------------------------------------------------------------
// 2. dinv[n] = rsqrt(1 + sum_s partial[s][n])
// ---------------------------------------------------------------------------
__global__ void k_finish_deg(const float* __restrict__ partial,
                             float* __restrict__ dinv, int N, int B) {
    int n = blockIdx.x * blockDim.x + threadIdx.x;
    if (n >= N) return;
    float acc = 1.0f;
    for (int s = 0; s < B; ++s) acc += partial[(size_t)s * N + n];
    dinv[n] = rsqrtf(acc);
}

// ---------------------------------------------------------------------------
// 3. g = dinv * (dropout(x) @ W)
// ---------------------------------------------------------------------------
__global__ __launch_bounds__(256) void k_h(const float* __restrict__ x,
                                           const float* __restrict__ W,
                                           const float* __restrict__ dinv,
                                           float* __restrict__ g,
                                           int N, int F) {
    const int wave = (int)((blockIdx.x * blockDim.x + threadIdx.x) >> 6);
    const int lane = threadIdx.x & 63;
    if (wave >= N) return;
    const int m = wave;
    const int f0 = lane * 8;

    const float4* xa = (const float4*)(x + (size_t)m * F + f0);
    float4 a0 = xa[0], a1 = xa[1];
    float va[8] = {a0.x, a0.y, a0.z, a0.w, a1.x, a1.y, a1.z, a1.w};

    const uint32_t jbase = (uint32_t)m * (uint32_t)F + (uint32_t)f0;
    float acc0 = 0.f, acc1 = 0.f;

#pragma unroll
    for (int t = 0; t < 8; ++t) {
        uint32_t o0, o1;
        threefry2x32(0u, jbase + (uint32_t)t, o0, o1);
        uint32_t bits = o0 ^ o1;
        float xv = (bits >> 31) ? 0.0f : va[t] * 2.0f;   // 1/(1-0.5)=2
        acc0 += xv * W[(f0 + t) * 2 + 0];
        acc1 += xv * W[(f0 + t) * 2 + 1];
    }
#pragma unroll
    for (int off = 32; off >= 1; off >>= 1) {
        acc0 += __shfl_xor(acc0, off);
        acc1 += __shfl_xor(acc1, off);
    }
    if (lane == 0) {
        float d = dinv[m];
        g[(size_t)m * 2 + 0] = d * acc0;
        g[(size_t)m * 2 + 1] = d * acc1;
    }
}

// ---------------------------------------------------------------------------
// 4. v2[e] = w[e] * g2[col[e]]   (coalesced gather pass; g is L2-resident)
// ---------------------------------------------------------------------------
__global__ void k_vpre(const int* __restrict__ col, const float* __restrict__ w,
                       const float* __restrict__ g, float2* __restrict__ v2, int E) {
    int e = blockIdx.x * blockDim.x + threadIdx.x;
    if (e >= E) return;
    float wv = w[e];
    float2 gv = ((const float2*)g)[col[e]];
    float2 o; o.x = wv * gv.x; o.y = wv * gv.y;
    v2[e] = o;
}

// ---------------------------------------------------------------------------
// 5. edge partitioned scan: unconditional int4 row stream; conditional 8B
//    v2[e] load on match; LDS accumulate; flush partial[s][n][2]
// ---------------------------------------------------------------------------
__global__ __launch_bounds__(512) void k_edge_scan(const int* __restrict__ row,
                                                   const float2* __restrict__ v2,
                                                   float* __restrict__ partial,
                                                   int E, int N, int R, int NP, int B) {
    __shared__ float sacc[R_EDGE * 2];
    const int p = blockIdx.x % NP;
    const int s = blockIdx.x / NP;
    const int pR = p * R;
    const unsigned rows = (unsigned)min(R, N - pR);
    for (int i = threadIdx.x; i < R * 2; i += 512) sacc[i] = 0.f;
    __syncthreads();

    const int E4 = E >> 2;
    const int4* rows4 = (const int4*)row;
    const long long q0 = (long long)E4 * s / B;
    const long long q1 = (long long)E4 * (s + 1) / B;
    for (long long q = q0 + threadIdx.x; q < q1; q += 512) {
        int4 r4 = rows4[q];
        long long e = q << 2;
        unsigned a0 = (unsigned)(r4.x - pR);
        unsigned a1 = (unsigned)(r4.y - pR);
        unsigned a2 = (unsigned)(r4.z - pR);
        unsigned a3 = (unsigned)(r4.w - pR);
        if (a0 < rows) { float2 t = v2[e + 0]; atomicAdd(&sacc[a0 * 2], t.x); atomicAdd(&sacc[a0 * 2 + 1], t.y); }
        if (a1 < rows) { float2 t = v2[e + 1]; atomicAdd(&sacc[a1 * 2], t.x); atomicAdd(&sacc[a1 * 2 + 1], t.y); }
        if (a2 < rows) { float2 t = v2[e + 2]; atomicAdd(&sacc[a2 * 2], t.x); atomicAdd(&sacc[a2 * 2 + 1], t.y); }
        if (a3 < rows) { float2 t = v2[e + 3]; atomicAdd(&sacc[a3 * 2], t.x); atomicAdd(&sacc[a3 * 2 + 1], t.y); }
    }
    if (s == B - 1) {
        for (int e = 4 * E4 + threadIdx.x; e < E; e += 512) {
            unsigned a = (unsigned)(row[e] - pR);
            if (a < rows) { float2 t = v2[e]; atomicAdd(&sacc[a * 2], t.x); atomicAdd(&sacc[a * 2 + 1], t.y); }
        }
    }
    __syncthreads();
    float* dst = partial + ((size_t)s * N + pR) * 2;
    for (int i = threadIdx.x; i < (int)rows * 2; i += 512) dst[i] = sacc[i];
}

// ---------------------------------------------------------------------------
// 6. out[n] = b + dinv[n] * (g[n] + sum_s partial[s][n])
// ---------------------------------------------------------------------------
__global__ void k_final(const float* __restrict__ partial,
                        const float* __restrict__ g,
                        const float* __restrict__ dinv,
                        const float* __restrict__ b,
                        float* __restrict__ out, int N, int B) {
    int n = blockIdx.x * blockDim.x + threadIdx.x;
    if (n >= N) return;
    const float2* p2 = (const float2*)partial;
    float2 gv = ((const float2*)g)[n];
    float a0 = gv.x, a1 = gv.y;
    for (int s = 0; s < B; ++s) {
        float2 pv = p2[(size_t)s * N + n];
        a0 += pv.x; a1 += pv.y;
    }
    float d = dinv[n];
    float2 o;
    o.x = b[0] + d * a0;
    o.y = b[1] + d * a1;
    ((float2*)out)[n] = o;
}

// ------------------------- fallback (atomic) path --------------------------
__global__ void k_deg_atomic(const int* __restrict__ row, const float* __restrict__ w,
                             float* __restrict__ deg, int E) {
    int e = blockIdx.x * blockDim.x + threadIdx.x;
    if (e < E) atomicAdd(&deg[row[e]], w[e]);
}
__global__ void k_dinv_fb(float* __restrict__ deg, int N) {
    int n = blockIdx.x * blockDim.x + threadIdx.x;
    if (n < N) deg[n] = rsqrtf(deg[n] + 1.0f);
}
__global__ void k_selfinit_fb(const float* __restrict__ g, const float* __restrict__ dinv,
                              const float* __restrict__ b, float* __restrict__ out, int N) {
    int n = blockIdx.x * blockDim.x + threadIdx.x;
    if (n < N) {
        float d = dinv[n];
        float2 gv = ((const float2*)g)[n];
        float2 o;
        o.x = b[0] + d * gv.x;
        o.y = b[1] + d * gv.y;
        ((float2*)out)[n] = o;
    }
}
__global__ void k_edge_atomic(const int* __restrict__ row, const int* __restrict__ col,
                              const float* __restrict__ w, const float* __restrict__ dinv,
                              const float* __restrict__ g, float* __restrict__ out, int E) {
    int e = blockIdx.x * blockDim.x + threadIdx.x;
    if (e < E) {
        int r = row[e], c = col[e];
        float nrm = dinv[r] * w[e];
        float2 gv = ((const float2*)g)[c];
        atomicAdd(&out[(size_t)r * 2 + 0], nrm * gv.x);
        atomicAdd(&out[(size_t)r * 2 + 1], nrm * gv.y);
    }
}

extern "C" void kernel_launch(void* const* d_in, const int* in_sizes, int n_in,
                              void* d_out, int out_size, void* d_ws, size_t ws_size,
                              hipStream_t stream) {
    const float* x  = (const float*)d_in[0];
    const int*   ei = (const int*)d_in[1];
    const float* ew = (const float*)d_in[2];
    const float* W  = (const float*)d_in[3];
    const float* b  = (const float*)d_in[4];
    float* out = (float*)d_out;

    const int C = in_sizes[4];            // 2
    const int F = in_sizes[3] / C;        // 512
    const int N = in_sizes[0] / F;        // 100000
    const int E = in_sizes[1] / 2;        // 3200000
    const int* row = ei;
    const int* col = ei + E;

    const int B_D = 32, B_E = 32;
    const int NP_D = (N + R_DEG - 1) / R_DEG;     // 8
    const int NP_E = (N + R_EDGE - 1) / R_EDGE;   // 16

    // ws layout (floats): dinv[N] | g[2N] | regionA (v2[2E] / partialD[B_D*N])
    //                     | regionB (partialE[B_E*2N])
    float* dinv = (float*)d_ws;
    float* g    = dinv + N;
    float* regA = g + (size_t)2 * N;
    size_t szA = (size_t)2 * E;
    if ((size_t)B_D * N > szA) szA = (size_t)B_D * N;
    float* regB = regA + szA;
    const size_t need = (size_t)3 * N + szA + (size_t)B_E * 2 * N;
    const size_t ws_floats = ws_size / sizeof(float);

    if (ws_floats >= need) {
        float*  partD = regA;
        float2* v2    = (float2*)regA;
        float*  partE = regB;
        k_deg_scan<<<NP_D * B_D, 512, 0, stream>>>(row, ew, partD, E, N, R_DEG, NP_D, B_D);
        k_finish_deg<<<(N + 255) / 256, 256, 0, stream>>>(partD, dinv, N, B_D);
        k_h<<<(N + 3) / 4, 256, 0, stream>>>(x, W, dinv, g, N, F);
        k_vpre<<<(E + 255) / 256, 256, 0, stream>>>(col, ew, g, v2, E);
        k_edge_scan<<<NP_E * B_E, 512, 0, stream>>>(row, v2, partE, E, N, R_EDGE, NP_E, B_E);
        k_final<<<(N + 255) / 256, 256, 0, stream>>>(partE, g, dinv, b, out, N, B_E);
    } else {
        // fallback: global-atomic path (round-3 verified)
        hipMemsetAsync(dinv, 0, (size_t)N * sizeof(float), stream);
        k_deg_atomic<<<(E + 255) / 256, 256, 0, stream>>>(row, ew, dinv, E);
        k_dinv_fb<<<(N + 255) / 256, 256, 0, stream>>>(dinv, N);
        k_h<<<(N + 3) / 4, 256, 0, stream>>>(x, W, dinv, g, N, F);
        k_selfinit_fb<<<(N + 255) / 256, 256, 0, stream>>>(g, dinv, b, out, N);
        k_edge_atomic<<<(E + 255) / 256, 256, 0, stream>>>(row, col, ew, dinv, g, out, E);
    }
}